// Round 11
// baseline (621.540 us; speedup 1.0000x reference)
//
#include <hip/hip_runtime.h>
#include <hip/hip_bf16.h>
#include <math.h>

#define B_    16
#define G_    4096
#define M_    128
#define D_    768
#define GI15  0.16431676725154983f   // 0.3^1.5
#define EPS_  1e-12f

typedef __attribute__((ext_vector_type(8))) short short8v;
typedef __attribute__((ext_vector_type(4))) float f32x4;
typedef unsigned short ushort_t;
typedef unsigned int   uint_t;

__device__ __forceinline__ ushort_t f2bf(float f) {   // RNE fp32->bf16 (finite)
    uint_t u = __float_as_uint(f);
    u += 0x7FFFu + ((u >> 16) & 1u);
    return (ushort_t)(u >> 16);
}
__device__ __forceinline__ float bf2f(ushort_t h) {
    return __uint_as_float(((uint_t)h) << 16);
}

// ---------------------------------------------------------------------------
// K-1: A-gen ONCE.  A4[b][gb][kc][arr][64g][32k] split-bf16 tiles
// (arr: 0=gto_hi 1=gto_lo 2=lgto_hi 3=lgto_lo), layout chosen so a wave's
// MFMA A-fragment load is a single contiguous 1024B global read.
// ---------------------------------------------------------------------------
__global__ __launch_bounds__(256) void k_agen(
        const float* __restrict__ dist,
        const int*   __restrict__ qn,
        const int*   __restrict__ ao,
        const float* __restrict__ zeta,
        ushort_t*    __restrict__ A4) {
    const int b = blockIdx.y, gb = blockIdx.x, tid = threadIdx.x;
    const int m = tid & 127, gh2 = tid >> 7;       // 2 threads per m
    const float q  = (float)qn[b * M_ + m];
    const float z  = zeta[ao[b * M_ + m]];
    const float z2 = z * z;
    const float c4 = 4.f * z2 * z2;
    const float c2 = 2.f * z2 * (2.f * q + 1.f);
    const float c0 = q * (q - 1.f);
    const int kc = m >> 5, k = m & 31;
    ushort_t* base = A4 + ((((size_t)(b * 64 + gb)) * 4 + kc) * 4) * 2048 + k;
    const float* dp = dist + ((size_t)(b * G_ + gb * 64 + gh2)) * M_ + m;
    #pragma unroll 4
    for (int r = 0; r < 32; ++r) {
        int g = r * 2 + gh2;
        float d  = dp[(size_t)(r * 2) * M_];
        float d2 = d * d;
        float e  = __expf(-z2 * d2);
        float p1 = (q < 1.5f) ? 1.f : ((q < 2.5f) ? d : d2);
        float gto  = p1 * e;
        float poly = fmaf(fmaf(c4, d2, -c2), d2, c0);
        float lg   = __fdividef(p1, d2) * e * poly;
        ushort_t gh = f2bf(gto);
        ushort_t lh = f2bf(lg);
        ushort_t* p = base + g * 32;
        p[0]    = gh;
        p[2048] = f2bf(gto - bf2f(gh));
        p[4096] = lh;
        p[6144] = f2bf(lg - bf2f(lh));
    }
}

// ---------------------------------------------------------------------------
// K0a: partial Gram matrices (NO atomics).  part[ch][b][128*128] in d_out
// scratch (67 MB < 402 MB; fully overwritten by k_gemm afterwards).
// ---------------------------------------------------------------------------
__global__ __launch_bounds__(256) void k_gram_part(
        const float* __restrict__ dist,
        const int*   __restrict__ qn,
        const int*   __restrict__ ao,
        const float* __restrict__ zeta,
        float*       __restrict__ part) {
    __shared__ float sg[64][M_];          // 32 KB
    __shared__ float pz2[M_], pq[M_];
    const int b = blockIdx.y, ch = blockIdx.x, tid = threadIdx.x;
    if (tid < M_) {
        pq[tid] = (float)qn[b * M_ + tid];
        float z = zeta[ao[b * M_ + tid]];
        pz2[tid] = z * z;
    }
    __syncthreads();
    {
        int m = tid & 127;
        float z2 = pz2[m], q = pq[m];
        for (int r = tid >> 7; r < 64; r += 2) {
            float d = dist[((size_t)(b * G_ + ch * 64 + r)) * M_ + m];
            float e  = __expf(-z2 * d * d);
            float p1 = (q < 1.5f) ? 1.f : ((q < 2.5f) ? d : d * d);
            sg[r][m] = p1 * e;
        }
    }
    __syncthreads();
    const int mi0 = (tid >> 4) * 8;
    const int mj0 = (tid & 15) * 8;
    float acc[8][8];
    #pragma unroll
    for (int i = 0; i < 8; ++i)
        #pragma unroll
        for (int j = 0; j < 8; ++j) acc[i][j] = 0.f;
    #pragma unroll 2
    for (int g = 0; g < 64; ++g) {
        float av[8], bv[8];
        *(float4*)&av[0] = *(const float4*)&sg[g][mi0];
        *(float4*)&av[4] = *(const float4*)&sg[g][mi0 + 4];
        *(float4*)&bv[0] = *(const float4*)&sg[g][mj0];
        *(float4*)&bv[4] = *(const float4*)&sg[g][mj0 + 4];
        #pragma unroll
        for (int i = 0; i < 8; ++i)
            #pragma unroll
            for (int j = 0; j < 8; ++j)
                acc[i][j] = fmaf(av[i], bv[j], acc[i][j]);
    }
    float* pp = part + ((size_t)(ch * B_ + b)) * (M_ * M_);
    #pragma unroll
    for (int i = 0; i < 8; ++i) {
        *(float4*)&pp[(mi0 + i) * M_ + mj0]     = make_float4(acc[i][0], acc[i][1], acc[i][2], acc[i][3]);
        *(float4*)&pp[(mi0 + i) * M_ + mj0 + 4] = make_float4(acc[i][4], acc[i][5], acc[i][6], acc[i][7]);
    }
}

// K0b: reduce 64 partials -> gram[b][128][128]
__global__ void k_gram_red(const float* __restrict__ part,
                           float*       __restrict__ gram) {
    int idx = blockIdx.x * 256 + threadIdx.x;     // < 262144
    float s = 0.f;
    #pragma unroll 8
    for (int ch = 0; ch < 64; ++ch)
        s += part[(size_t)ch * (B_ * M_ * M_) + idx];
    gram[idx] = s;
}

// ---------------------------------------------------------------------------
// K1: per-(b,d-tile): coeff col-norm + Gram quadratic form -> final column
// factor; exports pre-split bf16 B' = table*prg[m]*rcn*scale as
// Bsplit[b][d][m] hi/lo, ready for k_gemm's swizzled LDS copy.
// ---------------------------------------------------------------------------
__global__ __launch_bounds__(256) void k_mosq(
        const float* __restrict__ gram,
        const int*   __restrict__ ao,
        const float* __restrict__ table,
        const float* __restrict__ Nel,
        ushort_t*    __restrict__ bhiG,
        ushort_t*    __restrict__ bloG) {
    __shared__ float sv[M_][64];     // 32 KB
    __shared__ float sGq[32][M_];    // 16 KB
    __shared__ float prg[M_];
    __shared__ float sred[4][64];
    __shared__ float srcn[64], scf[64];
    const int b = blockIdx.y, d0 = blockIdx.x * 64, tid = threadIdx.x;
    const int dl = tid & 63, quad = tid >> 6;
    const float* gb = gram + (size_t)b * M_ * M_;
    if (tid < M_)
        prg[tid] = 1.f / (fmaxf(sqrtf(gb[tid * M_ + tid]), EPS_) * GI15);
    #pragma unroll 4
    for (int k = 0; k < 32; ++k) {
        int m = quad * 32 + k;
        sv[m][dl] = table[(size_t)ao[b * M_ + m] * D_ + d0 + dl];
    }
    __syncthreads();
    {
        float cs = 0.f;
        #pragma unroll 4
        for (int k = 0; k < 32; ++k) { float v = sv[quad * 32 + k][dl]; cs = fmaf(v, v, cs); }
        sred[quad][dl] = cs;
    }
    __syncthreads();
    if (quad == 0)
        srcn[dl] = 1.f / fmaxf(sqrtf(sred[0][dl] + sred[1][dl] + sred[2][dl] + sred[3][dl]), EPS_);
    #pragma unroll 4
    for (int k = 0; k < 32; ++k) { int m = quad * 32 + k; sv[m][dl] *= prg[m]; }
    __syncthreads();
    float acc = 0.f;
    for (int qt = 0; qt < 4; ++qt) {
        for (int e = tid; e < 32 * M_; e += 256)
            sGq[e >> 7][e & 127] = gb[(qt * 32 + (e >> 7)) * M_ + (e & 127)];
        __syncthreads();
        #pragma unroll
        for (int mr8 = 0; mr8 < 8; ++mr8) {
            int mr = quad * 8 + mr8;
            float t0 = 0.f, t1 = 0.f, t2 = 0.f, t3 = 0.f;
            #pragma unroll 4
            for (int mc = 0; mc < M_; mc += 4) {
                t0 = fmaf(sGq[mr][mc],     sv[mc][dl],     t0);
                t1 = fmaf(sGq[mr][mc + 1], sv[mc + 1][dl], t1);
                t2 = fmaf(sGq[mr][mc + 2], sv[mc + 2][dl], t2);
                t3 = fmaf(sGq[mr][mc + 3], sv[mc + 3][dl], t3);
            }
            acc = fmaf(sv[qt * 32 + mr][dl], (t0 + t1) + (t2 + t3), acc);
        }
        __syncthreads();
    }
    sred[quad][dl] = acc;
    __syncthreads();
    if (quad == 0) {
        float qf  = fmaxf(sred[0][dl] + sred[1][dl] + sred[2][dl] + sred[3][dl], 0.f);
        float rcn = srcn[dl];
        float mo  = rcn * sqrtf(qf);
        scf[dl] = sqrtf(Nel[b] / (float)D_) / fmaxf(mo, EPS_) * rcn;
    }
    __syncthreads();
    {
        float cfv = scf[dl];
        ushort_t* bh = bhiG + ((size_t)b * D_ + d0 + dl) * M_;
        ushort_t* bl = bloG + ((size_t)b * D_ + d0 + dl) * M_;
        #pragma unroll
        for (int mq = 0; mq < 4; ++mq) {
            int mb = quad * 32 + mq * 8;
            ushort_t h[8], l[8];
            #pragma unroll
            for (int r = 0; r < 8; ++r) {
                float v = sv[mb + r][dl] * cfv;
                h[r] = f2bf(v);
                l[r] = f2bf(v - bf2f(h[r]));
            }
            *(uint4*)&bh[mb] = *(const uint4*)&h[0];
            *(uint4*)&bl[mb] = *(const uint4*)&l[0];
        }
    }
}

// ---------------------------------------------------------------------------
// K2: MFMA GEMM.  64g x 128d per block, 512 threads = 8 waves.  B' staged
// once to LDS (swizzled); A-frags read DIRECTLY global->VGPR from k_agen's
// tiles (1024B contiguous per wave-load, L2/L3-resident).  NO barriers in
// the K-loop -> waves pipeline freely.
// ---------------------------------------------------------------------------
__global__ __launch_bounds__(512, 4) void k_gemm(
        const ushort_t* __restrict__ A4,
        const ushort_t* __restrict__ bhiG,
        const ushort_t* __restrict__ bloG,
        float*       __restrict__ out) {
    __shared__ ushort_t sBh[16384], sBl[16384];    // [128d][128k] swizzled
    const int tid = threadIdx.x;
    const int b  = blockIdx.z;
    const int g0 = blockIdx.y * 64;
    const int d0 = blockIdx.x * 128;

    // ---- stage B' (linear global read, swizzled LDS write) ----
    {
        const uint_t* gh = (const uint_t*)(bhiG + ((size_t)b * D_ + d0) * M_);
        const uint_t* gl = (const uint_t*)(bloG + ((size_t)b * D_ + d0) * M_);
        #pragma unroll
        for (int p = 0; p < 16; ++p) {
            int j = p * 512 + tid;                 // dword index < 8192
            int drow   = j >> 6;                   // 0..127 (64 dwords/row)
            int inrow4 = (j & 63) << 2;
            int tgt = drow * 256 + (inrow4 ^ ((drow & 7) << 4));
            *(uint_t*)((char*)sBh + tgt) = gh[j];
            *(uint_t*)((char*)sBl + tgt) = gl[j];
        }
    }

    const int lane = tid & 63, w = tid >> 6;       // 8 waves
    const int gsub  = (w & 3) * 16;                // g-subtile of this wave
    const int dhalf = (w >> 2) * 64;               // d-half of this wave
    const int lrow = lane & 15, lk8 = (lane >> 4) * 8;
    f32x4 accm[4], accl[4];
    #pragma unroll
    for (int t = 0; t < 4; ++t) {
        accm[t] = (f32x4){0.f, 0.f, 0.f, 0.f};
        accl[t] = (f32x4){0.f, 0.f, 0.f, 0.f};
    }
    // per-(b,gb) A chunk; frag base for this lane (row = gsub+lrow, k8)
    const ushort_t* Ab = A4 + ((size_t)(b * 64 + blockIdx.y)) * 32768
                            + (gsub + lrow) * 32 + lk8;
    __syncthreads();

    #pragma unroll
    for (int kc = 0; kc < 4; ++kc) {
        const ushort_t* Ak = Ab + kc * 8192;
        short8v agh = *(const short8v*)&Ak[0];
        short8v agl = *(const short8v*)&Ak[2048];
        short8v alh = *(const short8v*)&Ak[4096];
        short8v all_= *(const short8v*)&Ak[6144];
        int kk2 = (kc * 32 + lk8) * 2;
        #pragma unroll
        for (int dt = 0; dt < 4; ++dt) {
            int dr = dhalf + dt * 16 + lrow;
            int off = dr * 256 + (kk2 ^ ((dr & 7) << 4));
            short8v bh = *(const short8v*)((const char*)sBh + off);
            short8v bl = *(const short8v*)((const char*)sBl + off);
            accm[dt] = __builtin_amdgcn_mfma_f32_16x16x32_bf16(agh, bh, accm[dt], 0, 0, 0);
            accm[dt] = __builtin_amdgcn_mfma_f32_16x16x32_bf16(agh, bl, accm[dt], 0, 0, 0);
            accm[dt] = __builtin_amdgcn_mfma_f32_16x16x32_bf16(agl, bh, accm[dt], 0, 0, 0);
            accl[dt] = __builtin_amdgcn_mfma_f32_16x16x32_bf16(alh, bh, accl[dt], 0, 0, 0);
            accl[dt] = __builtin_amdgcn_mfma_f32_16x16x32_bf16(alh, bl, accl[dt], 0, 0, 0);
            accl[dt] = __builtin_amdgcn_mfma_f32_16x16x32_bf16(all_, bh, accl[dt], 0, 0, 0);
        }
    }

    // ---- store: C/D layout col=lane&15 (d), row=(lane>>4)*4+reg (g) ----
    const size_t HALF = (size_t)B_ * G_ * D_;
    const int grow = g0 + gsub + (lane >> 4) * 4;
    #pragma unroll
    for (int dt = 0; dt < 4; ++dt) {
        int dcol = d0 + dhalf + dt * 16 + lrow;
        #pragma unroll
        for (int r = 0; r < 4; ++r) {
            size_t off = ((size_t)(b * G_) + grow + r) * D_ + dcol;
            out[off]        = accm[dt][r];
            out[HALF + off] = accl[dt][r];
        }
    }
}

// ---------------------------------------------------------------------------
extern "C" void kernel_launch(void* const* d_in, const int* in_sizes, int n_in,
                              void* d_out, int out_size, void* d_ws, size_t ws_size,
                              hipStream_t stream) {
    const float* dist  = (const float*)d_in[0];
    const int*   qn    = (const int*)  d_in[1];
    const int*   ao    = (const int*)  d_in[2];
    const float* Nel   = (const float*)d_in[3];
    const float* table = (const float*)d_in[4];
    const float* zeta  = (const float*)d_in[5];
    float* out = (float*)d_out;
    char*  wsb = (char*)d_ws;

    // ws layout (bytes) -- NON-OVERLAPPING (round-10 bug: blo/A4 overlapped bhi):
    //   gram [0, 1 MiB)          : 262144 floats
    //   bhi  [1 MiB, 4 MiB)      : 16*768*128 ushorts = 3 MiB
    //   blo  [4 MiB, 7 MiB)      : 3 MiB
    //   A4   [8 MiB, 72 MiB)     : 64 MiB
    float*    gram = (float*)wsb;
    ushort_t* bhi  = (ushort_t*)(wsb + (size_t)(1u << 20));
    ushort_t* blo  = (ushort_t*)(wsb + (size_t)(4u << 20));
    ushort_t* A4   = (ushort_t*)(wsb + (size_t)(8u << 20));
    float*    part = out;                               // 67 MB scratch in d_out

    k_agen<<<dim3(64, B_), 256, 0, stream>>>(dist, qn, ao, zeta, A4);
    k_gram_part<<<dim3(64, B_), 256, 0, stream>>>(dist, qn, ao, zeta, part);
    k_gram_red<<<1024, 256, 0, stream>>>(part, gram);
    k_mosq<<<dim3(D_ / 64, B_), 256, 0, stream>>>(gram, ao, table, Nel, bhi, blo);
    k_gemm<<<dim3(D_ / 128, G_ / 64, B_), 512, 0, stream>>>(A4, bhi, blo, out);
}

// Round 12
// 592.926 us; speedup vs baseline: 1.0483x; 1.0483x over previous
//
#include <hip/hip_runtime.h>
#include <hip/hip_bf16.h>
#include <math.h>

#define B_    16
#define G_    4096
#define M_    128
#define D_    768
#define GI15  0.16431676725154983f   // 0.3^1.5
#define EPS_  1e-12f

typedef __attribute__((ext_vector_type(8))) short short8v;
typedef __attribute__((ext_vector_type(4))) float f32x4;
typedef unsigned short ushort_t;
typedef unsigned int   uint_t;

__device__ __forceinline__ ushort_t f2bf(float f) {   // RNE fp32->bf16 (finite)
    uint_t u = __float_as_uint(f);
    u += 0x7FFFu + ((u >> 16) & 1u);
    return (ushort_t)(u >> 16);
}
__device__ __forceinline__ float bf2f(ushort_t h) {
    return __uint_as_float(((uint_t)h) << 16);
}

// ---------------------------------------------------------------------------
// K0: FUSED A-gen + partial Gram.  Computes gto/l_gto once per (b,g-tile):
//  (a) stores split-bf16 A4[b][gb][kc][arr][64g][32k] (contiguous wave frags),
//  (b) stages gto in LDS and accumulates the 64-g partial Gram -> part.
// ---------------------------------------------------------------------------
__global__ __launch_bounds__(256) void k_agen(
        const float* __restrict__ dist,
        const int*   __restrict__ qn,
        const int*   __restrict__ ao,
        const float* __restrict__ zeta,
        ushort_t*    __restrict__ A4,
        float*       __restrict__ part) {
    __shared__ float sg[64][M_];          // 32 KB
    const int b = blockIdx.y, gb = blockIdx.x, tid = threadIdx.x;
    const int m = tid & 127, gh2 = tid >> 7;       // 2 threads per m
    const float q  = (float)qn[b * M_ + m];
    const float z  = zeta[ao[b * M_ + m]];
    const float z2 = z * z;
    const float c4 = 4.f * z2 * z2;
    const float c2 = 2.f * z2 * (2.f * q + 1.f);
    const float c0 = q * (q - 1.f);
    const int kc = m >> 5, k = m & 31;
    ushort_t* base = A4 + ((((size_t)(b * 64 + gb)) * 4 + kc) * 4) * 2048 + k;
    const float* dp = dist + ((size_t)(b * G_ + gb * 64 + gh2)) * M_ + m;
    #pragma unroll 4
    for (int r = 0; r < 32; ++r) {
        int g = r * 2 + gh2;
        float d  = dp[(size_t)(r * 2) * M_];
        float d2 = d * d;
        float e  = __expf(-z2 * d2);
        float p1 = (q < 1.5f) ? 1.f : ((q < 2.5f) ? d : d2);
        float gto  = p1 * e;
        float poly = fmaf(fmaf(c4, d2, -c2), d2, c0);
        float lg   = __fdividef(p1, d2) * e * poly;
        sg[g][m] = gto;
        ushort_t gh = f2bf(gto);
        ushort_t lh = f2bf(lg);
        ushort_t* p = base + g * 32;
        p[0]    = gh;
        p[2048] = f2bf(gto - bf2f(gh));
        p[4096] = lh;
        p[6144] = f2bf(lg - bf2f(lh));
    }
    __syncthreads();
    // ---- partial Gram from the staged tile ----
    const int mi0 = (tid >> 4) * 8;
    const int mj0 = (tid & 15) * 8;
    float acc[8][8];
    #pragma unroll
    for (int i = 0; i < 8; ++i)
        #pragma unroll
        for (int j = 0; j < 8; ++j) acc[i][j] = 0.f;
    #pragma unroll 2
    for (int g = 0; g < 64; ++g) {
        float av[8], bv[8];
        *(float4*)&av[0] = *(const float4*)&sg[g][mi0];
        *(float4*)&av[4] = *(const float4*)&sg[g][mi0 + 4];
        *(float4*)&bv[0] = *(const float4*)&sg[g][mj0];
        *(float4*)&bv[4] = *(const float4*)&sg[g][mj0 + 4];
        #pragma unroll
        for (int i = 0; i < 8; ++i)
            #pragma unroll
            for (int j = 0; j < 8; ++j)
                acc[i][j] = fmaf(av[i], bv[j], acc[i][j]);
    }
    float* pp = part + ((size_t)(gb * B_ + b)) * (M_ * M_);
    #pragma unroll
    for (int i = 0; i < 8; ++i) {
        *(float4*)&pp[(mi0 + i) * M_ + mj0]     = make_float4(acc[i][0], acc[i][1], acc[i][2], acc[i][3]);
        *(float4*)&pp[(mi0 + i) * M_ + mj0 + 4] = make_float4(acc[i][4], acc[i][5], acc[i][6], acc[i][7]);
    }
}

// K0b: reduce 64 partials -> gram[b][128][128]
__global__ void k_gram_red(const float* __restrict__ part,
                           float*       __restrict__ gram) {
    int idx = blockIdx.x * 256 + threadIdx.x;     // < 262144
    float s = 0.f;
    #pragma unroll 8
    for (int ch = 0; ch < 64; ++ch)
        s += part[(size_t)ch * (B_ * M_ * M_) + idx];
    gram[idx] = s;
}

// ---------------------------------------------------------------------------
// K1: per-(b,d-tile): coeff col-norm + Gram quadratic form -> final column
// factor; exports pre-split bf16 B' = table*prg[m]*rcn*scale as
// Bsplit[b][d][m] hi/lo, ready for k_gemm's swizzled LDS copy.
// ---------------------------------------------------------------------------
__global__ __launch_bounds__(256) void k_mosq(
        const float* __restrict__ gram,
        const int*   __restrict__ ao,
        const float* __restrict__ table,
        const float* __restrict__ Nel,
        ushort_t*    __restrict__ bhiG,
        ushort_t*    __restrict__ bloG) {
    __shared__ float sv[M_][64];     // 32 KB
    __shared__ float sGq[32][M_];    // 16 KB
    __shared__ float prg[M_];
    __shared__ float sred[4][64];
    __shared__ float srcn[64], scf[64];
    const int b = blockIdx.y, d0 = blockIdx.x * 64, tid = threadIdx.x;
    const int dl = tid & 63, quad = tid >> 6;
    const float* gb = gram + (size_t)b * M_ * M_;
    if (tid < M_)
        prg[tid] = 1.f / (fmaxf(sqrtf(gb[tid * M_ + tid]), EPS_) * GI15);
    #pragma unroll 4
    for (int k = 0; k < 32; ++k) {
        int m = quad * 32 + k;
        sv[m][dl] = table[(size_t)ao[b * M_ + m] * D_ + d0 + dl];
    }
    __syncthreads();
    {
        float cs = 0.f;
        #pragma unroll 4
        for (int k = 0; k < 32; ++k) { float v = sv[quad * 32 + k][dl]; cs = fmaf(v, v, cs); }
        sred[quad][dl] = cs;
    }
    __syncthreads();
    if (quad == 0)
        srcn[dl] = 1.f / fmaxf(sqrtf(sred[0][dl] + sred[1][dl] + sred[2][dl] + sred[3][dl]), EPS_);
    #pragma unroll 4
    for (int k = 0; k < 32; ++k) { int m = quad * 32 + k; sv[m][dl] *= prg[m]; }
    __syncthreads();
    float acc = 0.f;
    for (int qt = 0; qt < 4; ++qt) {
        for (int e = tid; e < 32 * M_; e += 256)
            sGq[e >> 7][e & 127] = gb[(qt * 32 + (e >> 7)) * M_ + (e & 127)];
        __syncthreads();
        #pragma unroll
        for (int mr8 = 0; mr8 < 8; ++mr8) {
            int mr = quad * 8 + mr8;
            float t0 = 0.f, t1 = 0.f, t2 = 0.f, t3 = 0.f;
            #pragma unroll 4
            for (int mc = 0; mc < M_; mc += 4) {
                t0 = fmaf(sGq[mr][mc],     sv[mc][dl],     t0);
                t1 = fmaf(sGq[mr][mc + 1], sv[mc + 1][dl], t1);
                t2 = fmaf(sGq[mr][mc + 2], sv[mc + 2][dl], t2);
                t3 = fmaf(sGq[mr][mc + 3], sv[mc + 3][dl], t3);
            }
            acc = fmaf(sv[qt * 32 + mr][dl], (t0 + t1) + (t2 + t3), acc);
        }
        __syncthreads();
    }
    sred[quad][dl] = acc;
    __syncthreads();
    if (quad == 0) {
        float qf  = fmaxf(sred[0][dl] + sred[1][dl] + sred[2][dl] + sred[3][dl], 0.f);
        float rcn = srcn[dl];
        float mo  = rcn * sqrtf(qf);
        scf[dl] = sqrtf(Nel[b] / (float)D_) / fmaxf(mo, EPS_) * rcn;
    }
    __syncthreads();
    {
        float cfv = scf[dl];
        ushort_t* bh = bhiG + ((size_t)b * D_ + d0 + dl) * M_;
        ushort_t* bl = bloG + ((size_t)b * D_ + d0 + dl) * M_;
        #pragma unroll
        for (int mq = 0; mq < 4; ++mq) {
            int mb = quad * 32 + mq * 8;
            ushort_t h[8], l[8];
            #pragma unroll
            for (int r = 0; r < 8; ++r) {
                float v = sv[mb + r][dl] * cfv;
                h[r] = f2bf(v);
                l[r] = f2bf(v - bf2f(h[r]));
            }
            *(uint4*)&bh[mb] = *(const uint4*)&h[0];
            *(uint4*)&bl[mb] = *(const uint4*)&l[0];
        }
    }
}

// ---------------------------------------------------------------------------
// K2: MFMA GEMM.  64g x 128d per block, 512 threads = 8 waves.  ALL 16
// A-frag loads issued at kernel entry (vmcnt FIFO -> latency hides under the
// B-stage + barrier); B' staged once to LDS (swizzled).  K-loop is pure
// MFMA + ds_read, no barriers, no exposed vmem latency.
// ---------------------------------------------------------------------------
__global__ __launch_bounds__(512, 4) void k_gemm(
        const ushort_t* __restrict__ A4,
        const ushort_t* __restrict__ bhiG,
        const ushort_t* __restrict__ bloG,
        float*       __restrict__ out) {
    __shared__ ushort_t sBh[16384], sBl[16384];    // [128d][128k] swizzled
    const int tid = threadIdx.x;
    const int b  = blockIdx.z;
    const int g0 = blockIdx.y * 64;
    const int d0 = blockIdx.x * 128;

    const int lane = tid & 63, w = tid >> 6;       // 8 waves
    const int gsub  = (w & 3) * 16;                // g-subtile of this wave
    const int dhalf = (w >> 2) * 64;               // d-half of this wave
    const int lrow = lane & 15, lk8 = (lane >> 4) * 8;

    // ---- issue ALL A-frag loads FIRST (latency hidden under B-stage) ----
    const ushort_t* Ab = A4 + ((size_t)(b * 64 + blockIdx.y)) * 32768
                            + (gsub + lrow) * 32 + lk8;
    short8v afr[16];
    #pragma unroll
    for (int kc = 0; kc < 4; ++kc) {
        const ushort_t* Ak = Ab + kc * 8192;
        afr[kc * 4 + 0] = *(const short8v*)&Ak[0];
        afr[kc * 4 + 1] = *(const short8v*)&Ak[2048];
        afr[kc * 4 + 2] = *(const short8v*)&Ak[4096];
        afr[kc * 4 + 3] = *(const short8v*)&Ak[6144];
    }

    // ---- stage B' (linear global read, swizzled LDS write) ----
    {
        const uint_t* gh = (const uint_t*)(bhiG + ((size_t)b * D_ + d0) * M_);
        const uint_t* gl = (const uint_t*)(bloG + ((size_t)b * D_ + d0) * M_);
        #pragma unroll
        for (int p = 0; p < 16; ++p) {
            int j = p * 512 + tid;                 // dword index < 8192
            int drow   = j >> 6;                   // 0..127 (64 dwords/row)
            int inrow4 = (j & 63) << 2;
            int tgt = drow * 256 + (inrow4 ^ ((drow & 7) << 4));
            *(uint_t*)((char*)sBh + tgt) = gh[j];
            *(uint_t*)((char*)sBl + tgt) = gl[j];
        }
    }

    f32x4 accm[4], accl[4];
    #pragma unroll
    for (int t = 0; t < 4; ++t) {
        accm[t] = (f32x4){0.f, 0.f, 0.f, 0.f};
        accl[t] = (f32x4){0.f, 0.f, 0.f, 0.f};
    }
    __syncthreads();

    #pragma unroll
    for (int kc = 0; kc < 4; ++kc) {
        short8v agh = afr[kc * 4 + 0];
        short8v agl = afr[kc * 4 + 1];
        short8v alh = afr[kc * 4 + 2];
        short8v all_= afr[kc * 4 + 3];
        int kk2 = (kc * 32 + lk8) * 2;
        #pragma unroll
        for (int dt = 0; dt < 4; ++dt) {
            int dr = dhalf + dt * 16 + lrow;
            int off = dr * 256 + (kk2 ^ ((dr & 7) << 4));
            short8v bh = *(const short8v*)((const char*)sBh + off);
            short8v bl = *(const short8v*)((const char*)sBl + off);
            accm[dt] = __builtin_amdgcn_mfma_f32_16x16x32_bf16(agh, bh, accm[dt], 0, 0, 0);
            accm[dt] = __builtin_amdgcn_mfma_f32_16x16x32_bf16(agh, bl, accm[dt], 0, 0, 0);
            accm[dt] = __builtin_amdgcn_mfma_f32_16x16x32_bf16(agl, bh, accm[dt], 0, 0, 0);
            accl[dt] = __builtin_amdgcn_mfma_f32_16x16x32_bf16(alh, bh, accl[dt], 0, 0, 0);
            accl[dt] = __builtin_amdgcn_mfma_f32_16x16x32_bf16(alh, bl, accl[dt], 0, 0, 0);
            accl[dt] = __builtin_amdgcn_mfma_f32_16x16x32_bf16(all_, bh, accl[dt], 0, 0, 0);
        }
    }

    // ---- store: C/D layout col=lane&15 (d), row=(lane>>4)*4+reg (g) ----
    const size_t HALF = (size_t)B_ * G_ * D_;
    const int grow = g0 + gsub + (lane >> 4) * 4;
    #pragma unroll
    for (int dt = 0; dt < 4; ++dt) {
        int dcol = d0 + dhalf + dt * 16 + lrow;
        #pragma unroll
        for (int r = 0; r < 4; ++r) {
            size_t off = ((size_t)(b * G_) + grow + r) * D_ + dcol;
            out[off]        = accm[dt][r];
            out[HALF + off] = accl[dt][r];
        }
    }
}

// ---------------------------------------------------------------------------
extern "C" void kernel_launch(void* const* d_in, const int* in_sizes, int n_in,
                              void* d_out, int out_size, void* d_ws, size_t ws_size,
                              hipStream_t stream) {
    const float* dist  = (const float*)d_in[0];
    const int*   qn    = (const int*)  d_in[1];
    const int*   ao    = (const int*)  d_in[2];
    const float* Nel   = (const float*)d_in[3];
    const float* table = (const float*)d_in[4];
    const float* zeta  = (const float*)d_in[5];
    float* out = (float*)d_out;
    char*  wsb = (char*)d_ws;

    // ws layout (bytes), non-overlapping:
    //   gram [0, 1 MiB) | bhi [1,4 MiB) | blo [4,7 MiB) | A4 [8,72 MiB)
    float*    gram = (float*)wsb;
    ushort_t* bhi  = (ushort_t*)(wsb + (size_t)(1u << 20));
    ushort_t* blo  = (ushort_t*)(wsb + (size_t)(4u << 20));
    ushort_t* A4   = (ushort_t*)(wsb + (size_t)(8u << 20));
    float*    part = out;                               // 67 MB scratch in d_out

    k_agen<<<dim3(64, B_), 256, 0, stream>>>(dist, qn, ao, zeta, A4, part);
    k_gram_red<<<1024, 256, 0, stream>>>(part, gram);
    k_mosq<<<dim3(D_ / 64, B_), 256, 0, stream>>>(gram, ao, table, Nel, bhi, blo);
    k_gemm<<<dim3(D_ / 128, G_ / 64, B_), 512, 0, stream>>>(A4, bhi, blo, out);
}